// Round 8
// baseline (226.845 us; speedup 1.0000x reference)
//
#include <hip/hip_runtime.h>
#include <hip/hip_bf16.h>

typedef short s16x8 __attribute__((ext_vector_type(8)));
typedef short s16x4 __attribute__((ext_vector_type(4)));
typedef float f32x4 __attribute__((ext_vector_type(4)));

#define TB 8            // batch elements per group
#define NBG 4           // groups per block (sequential)
#define HALO 46         // gtile positions per batch (pos -2 .. 43)
#define GSTRIDE 2216    // shorts per batch in gtile (8*odd: conflict-free P3 reads / P2 writes)
#define USTRIDE 50      // floats per batch in u_s halo
#define NT 3            // stage-2 N tiles (48 cols, >=37 zero-padded; k=240 = b2 row)
#define GT_SHORTS (TB * GSTRIDE)       // 17728 shorts = 35456 B

__device__ __forceinline__ unsigned short f2bf(float f) {
    unsigned int u = __float_as_uint(f);
    u += 0x7fff + ((u >> 16) & 1);   // RNE
    return (unsigned short)(u >> 16);
}

// packed f32x2 -> bf16x2 (v_cvt_pk_bf16_f32, RNE)
__device__ __forceinline__ unsigned int pk_bf16(float lo, float hi) {
    float2 f; f.x = lo; f.y = hi;
    __hip_bfloat162 h = __float22bfloat162_rn(f);
    union { __hip_bfloat162 b; unsigned int u; } c;
    c.b = h;
    return c.u;
}

// (256,3): 3 blocks/CU (empirically OccupancyPercent == 2nd arg).
// Reg cap ~168; persistent aW2 96 + aW1 20 + w3v 12 + peak transients ~30 (split bg) ~= 162 -> no spill.
// Guard metric: WRITE_SIZE must stay 10.24 MB.
__global__ __launch_bounds__(256, 3) void lorenz96_fused(
    const float* __restrict__ u,
    const float* __restrict__ coeff,
    const float* __restrict__ W1,
    const float* __restrict__ b1,
    const float* __restrict__ W2,
    const float* __restrict__ b2,
    const float* __restrict__ W3,
    const float* __restrict__ b3,
    float* __restrict__ out)
{
    // LDS: gtile 35456 (aliases W2 staging) + u_sbuf 3200 + out1_s 1280 = 39936 B -> 3 blocks/CU
    __shared__ __align__(16) unsigned short gtile[GT_SHORTS];
    __shared__ __align__(16) float u_sbuf[2][TB * USTRIDE];   // u_s[b][k] = u[b][(k+36)%40]
    __shared__ float out1_s[TB * 40];

    unsigned short* B_lds = gtile;   // alias: consumed into regs before gtile is written

    const int t    = threadIdx.x;
    const int lane = t & 63;
    const int wave = t >> 6;
    const int quad = lane >> 4;
    const int l15  = lane & 15;

    const int b0_block = blockIdx.x * (TB * NBG);

    // ---------- init 0a: W2 staging, pre-swizzled; k=240 carries b2 (bias row, B supplies 1.0) ----------
    // W2eff[o][k = tap*48 + c] = W2[o][c][tap]; lane holds [o = nt*16+l15][k = ks*32+quad*8+j]
    for (int g = t; g < NT * 8 * 64; g += 256) {
        int lg = g & 63;
        int ks = (g >> 6) & 7;
        int nt = g >> 9;
        int o  = nt * 16 + (lg & 15);
        int kb = ks * 32 + (lg >> 4) * 8;
        s16x8 pack = {0, 0, 0, 0, 0, 0, 0, 0};
        #pragma unroll
        for (int j = 0; j < 8; ++j) {
            int k = kb + j;
            if (o < 37) {
                if (k < 240) {
                    int c = k % 48, tap = k / 48;
                    pack[j] = (short)f2bf(W2[o * 240 + c * 5 + tap]);
                } else if (k == 240) {
                    pack[j] = (short)f2bf(b2[o]);
                }
            }
        }
        *(s16x8*)&B_lds[g * 8] = pack;
    }

    // ---------- init 0b: conv1 A-fragments (W1 + fused b1 at k=5) ----------
    // tiles: T0=ch0-15, T1=ch16-31, T2=ch32-47, T3 rows8-15=ch48-55, T4=ch56-71.
    // GLU in-lane: T1 rows8-15 x T3 rows8-15; T2 x T4 (same quad,reg).
    s16x8 aW1[5];
    {
        int chs[5];
        chs[0] = l15; chs[1] = 16 + l15; chs[2] = 32 + l15;
        chs[3] = (l15 >= 8) ? 40 + l15 : -1;
        chs[4] = 56 + l15;
        #pragma unroll
        for (int mt = 0; mt < 5; ++mt) {
            s16x8 a = {0, 0, 0, 0, 0, 0, 0, 0};
            int ch = chs[mt];
            if (quad == 0 && ch >= 0) {
                #pragma unroll
                for (int j = 0; j < 5; ++j) a[j] = (short)f2bf(W1[ch * 5 + j]);
                a[5] = (short)f2bf(b1[ch]);   // bias slot; B supplies 1.0 at k=5
            }
            aW1[mt] = a;
        }
    }

    // ---------- init 0c: epilogue constants (b2 folded into GEMM; only W3 left) ----------
    float w3v[NT][4];
    #pragma unroll
    for (int nt = 0; nt < NT; ++nt)
        #pragma unroll
        for (int r = 0; r < 4; ++r) {
            int o = nt * 16 + quad * 4 + r;
            w3v[nt][r] = (o < 37) ? W3[o] : 0.f;
        }
    const float b3v = b3[0];
    float cf[18];
    #pragma unroll
    for (int i = 0; i < 18; ++i) cf[i] = coeff[i];

    // ---------- helpers ----------
    auto prestage_u = [&](int grp) {   // stage u halo for group grp into u_sbuf[grp&1]
        for (int idx = t; idx < TB * USTRIDE; idx += 256) {
            int b = idx / USTRIDE, k = idx - b * USTRIDE;
            int gi = k + 36; gi -= (gi >= 40) ? 40 : 0; gi -= (gi >= 40) ? 40 : 0;
            u_sbuf[grp & 1][idx] = u[(size_t)(b0_block + grp * TB + b) * 40 + gi];
        }
    };

    auto poly = [&](int grp) {         // polynomial term for this wave's output rows
        const float* u_s = u_sbuf[grp & 1];
        #pragma unroll
        for (int pass = 0; pass < 2; ++pass) {
            int i = pass ? 4 : quad;
            bool act = pass ? (quad == 0) : true;
            if (act) {
                int m = (wave + 4 * i) * 16 + l15;
                int p = m >> 3, b = m & 7;
                const float* us = &u_s[b * USTRIDE + p];
                float um2 = us[2], um1 = us[3], u0 = us[4], up1 = us[5], up2 = us[6];
                float r = cf[0] + cf[1]*um2 + cf[2]*um1 + cf[3]*u0 + cf[4]*up1 + cf[5]*up2
                        + cf[6]*um2*um2 + cf[7]*um1*um1 + cf[8]*u0*u0 + cf[9]*up1*up1 + cf[10]*up2*up2
                        + cf[11]*um2*um1 + cf[12]*um1*u0 + cf[13]*u0*up1 + cf[14]*up1*up2
                        + cf[15]*um2*u0 + cf[16]*um1*up1 + cf[17]*u0*up2;
                out1_s[m] = r;
            }
        }
    };

    auto phase2 = [&](int grp) {       // conv1 via MFMA + GLU -> gtile
        const float* u_s = u_sbuf[grp & 1];
        #pragma unroll
        for (int i = 0; i < 6; ++i) {
            const int ct  = wave + 4 * i;              // 24 col-tiles (368 live cols)
            const int col = ct * 16 + l15;
            const int b = col & 7, h = col >> 3;
            const int hc = (h < HALO) ? h : 0;
            s16x8 bU = {0, 0, 0, 0, 0, 0, 0, 0};
            if (quad == 0) {
                const float* us = &u_s[b * USTRIDE + hc];   // taps u[(h-4+j)%40], j=0..4
                union { s16x8 v; unsigned int w[4]; } bu;
                bu.w[0] = pk_bf16(us[0], us[1]);
                bu.w[1] = pk_bf16(us[2], us[3]);
                bu.w[2] = pk_bf16(us[4], 1.0f);            // 1.0 -> bias slot k=5
                bu.w[3] = 0;
                bU = bu.v;
            }
            f32x4 a0 = {0.f,0.f,0.f,0.f}, a1 = a0, a2 = a0, a3 = a0, a4 = a0;
            a0 = __builtin_amdgcn_mfma_f32_16x16x32_bf16(aW1[0], bU, a0, 0, 0, 0);
            a1 = __builtin_amdgcn_mfma_f32_16x16x32_bf16(aW1[1], bU, a1, 0, 0, 0);
            a2 = __builtin_amdgcn_mfma_f32_16x16x32_bf16(aW1[2], bU, a2, 0, 0, 0);
            a3 = __builtin_amdgcn_mfma_f32_16x16x32_bf16(aW1[3], bU, a3, 0, 0, 0);
            a4 = __builtin_amdgcn_mfma_f32_16x16x32_bf16(aW1[4], bU, a4, 0, 0, 0);
            if (h < HALO) {
                float v0[4], v1[4], v2[4];
                #pragma unroll
                for (int r = 0; r < 4; ++r) {
                    v0[r] = fmaxf(a0[r], 0.f);
                    v1[r] = fmaxf(a1[r], 0.f);
                    if (quad >= 2) v1[r] *= fmaxf(a3[r], 0.f);          // ch24-31 gate
                    v2[r] = fmaxf(a2[r], 0.f) * fmaxf(a4[r], 0.f);      // ch32-47 gate
                }
                union { s16x4 v; unsigned int w[2]; } w0, w1, w2;
                w0.w[0] = pk_bf16(v0[0], v0[1]); w0.w[1] = pk_bf16(v0[2], v0[3]);
                w1.w[0] = pk_bf16(v1[0], v1[1]); w1.w[1] = pk_bf16(v1[2], v1[3]);
                w2.w[0] = pk_bf16(v2[0], v2[1]); w2.w[1] = pk_bf16(v2[2], v2[3]);
                unsigned short* gp = &gtile[b * GSTRIDE + h * 48 + quad * 4];
                *(s16x4*)(gp)      = w0.v;
                *(s16x4*)(gp + 16) = w1.v;
                *(s16x4*)(gp + 32) = w2.v;
            }
        }
    };

    // ---------- prologue ----------
    prestage_u(0);
    __syncthreads();   // B_lds + u_sbuf[0] ready

    // stage-2 A-fragments (W2 + b2 row), all 3 N-tiles per wave -> 3 independent MFMA chains
    s16x8 aW2[NT][8];
    #pragma unroll
    for (int nt = 0; nt < NT; ++nt)
        #pragma unroll
        for (int ks = 0; ks < 8; ++ks)
            aW2[nt][ks] = *(const s16x8*)&B_lds[((nt * 8 + ks) * 64 + lane) * 8];

    // ---------- main loop: 2 barriers per group; cross-block overlap fills the windows ----------
    for (int g = 0; g < NBG; ++g) {
        const int b0 = b0_block + g * TB;

        __syncthreads();   // barrier A: aW2 loads done (g0) / P3(g-1) gtile+out1 reads done

        poly(g);
        phase2(g);
        if (g + 1 < NBG) prestage_u(g + 1);

        __syncthreads();   // barrier B: gtile + out1_s ready

        // phase 3: each wave: 5 M-tiles x all 3 N-tiles (3 indep chains; bg split in halves)
        #pragma unroll
        for (int i = 0; i < 5; ++i) {
            const int mt = wave + 4 * i;               // 20 M-tiles (320 G-rows)
            const int m  = mt * 16 + l15;
            const int p  = m >> 3, b = m & 7;
            const unsigned short* gbase = &gtile[b * GSTRIDE + p * 48 + quad * 8];
            f32x4 c0 = {0.f,0.f,0.f,0.f}, c1 = c0, c2 = c0;
            {   // first half: ks 0..3
                s16x8 bg[4];
                #pragma unroll
                for (int ks = 0; ks < 4; ++ks) bg[ks] = *(const s16x8*)(gbase + ks * 32);
                #pragma unroll
                for (int ks = 0; ks < 4; ++ks) {
                    c0 = __builtin_amdgcn_mfma_f32_16x16x32_bf16(aW2[0][ks], bg[ks], c0, 0, 0, 0);
                    c1 = __builtin_amdgcn_mfma_f32_16x16x32_bf16(aW2[1][ks], bg[ks], c1, 0, 0, 0);
                    c2 = __builtin_amdgcn_mfma_f32_16x16x32_bf16(aW2[2][ks], bg[ks], c2, 0, 0, 0);
                }
            }
            {   // second half: ks 4..7 (bias row k=240 <-> ks=7, quad=2, j=0 must read 1.0)
                s16x8 bg[4];
                #pragma unroll
                for (int ks = 0; ks < 4; ++ks) bg[ks] = *(const s16x8*)(gbase + (4 + ks) * 32);
                if (quad == 2) { s16x8 b7 = bg[3]; b7[0] = (short)0x3F80; bg[3] = b7; }
                #pragma unroll
                for (int ks = 0; ks < 4; ++ks) {
                    c0 = __builtin_amdgcn_mfma_f32_16x16x32_bf16(aW2[0][4 + ks], bg[ks], c0, 0, 0, 0);
                    c1 = __builtin_amdgcn_mfma_f32_16x16x32_bf16(aW2[1][4 + ks], bg[ks], c1, 0, 0, 0);
                    c2 = __builtin_amdgcn_mfma_f32_16x16x32_bf16(aW2[2][4 + ks], bg[ks], c2, 0, 0, 0);
                }
            }
            // epilogue: c already includes b2; sum relu(h2)*W3 over channels, 2 shuffles
            float s = 0.f;
            #pragma unroll
            for (int r = 0; r < 4; ++r) {
                s += fmaxf(c0[r], 0.f) * w3v[0][r];
                s += fmaxf(c1[r], 0.f) * w3v[1][r];
                s += fmaxf(c2[r], 0.f) * w3v[2][r];
            }
            s += __shfl_xor(s, 16, 64);                // sum the 4 quads
            s += __shfl_xor(s, 32, 64);
            if (lane < 16) {
                int mo = mt * 16 + lane;
                out[(size_t)(b0 + (mo & 7)) * 40 + (mo >> 3)] = s + b3v + out1_s[mo];
            }
        }
    }
}

extern "C" void kernel_launch(void* const* d_in, const int* in_sizes, int n_in,
                              void* d_out, int out_size, void* d_ws, size_t ws_size,
                              hipStream_t stream) {
    // inputs: 0=t(unused), 1=u, 2=coeff, 3=W1, 4=b1, 5=W2, 6=b2, 7=W3, 8=b3
    const float* u     = (const float*)d_in[1];
    const float* coeff = (const float*)d_in[2];
    const float* W1    = (const float*)d_in[3];
    const float* b1    = (const float*)d_in[4];
    const float* W2    = (const float*)d_in[5];
    const float* b2    = (const float*)d_in[6];
    const float* W3    = (const float*)d_in[7];
    const float* b3    = (const float*)d_in[8];
    float* out = (float*)d_out;

    const int n_batch = in_sizes[1] / 40;            // 65536
    const int grid = n_batch / (TB * NBG);           // 2048 blocks
    lorenz96_fused<<<grid, 256, 0, stream>>>(u, coeff, W1, b1, W2, b2, W3, b3, out);
}

// Round 9
// 186.864 us; speedup vs baseline: 1.2140x; 1.2140x over previous
//
#include <hip/hip_runtime.h>
#include <hip/hip_bf16.h>

typedef short s16x8 __attribute__((ext_vector_type(8)));
typedef short s16x4 __attribute__((ext_vector_type(4)));
typedef float f32x4 __attribute__((ext_vector_type(4)));

#define TB 8            // batch elements per group
#define NBG 16          // groups per block (sequential); grid 512 = exactly 2 blocks/CU
#define HALO 46         // gtile positions per batch (pos -2 .. 43)
#define GSTRIDE 2216    // shorts per batch in gtile (8*odd: conflict-decorrelated)
#define USTRIDE 50      // floats per batch in u_s halo
#define NT 3            // stage-2 N tiles (48 cols, >=37 zero-padded; k=240 = b2 row)
#define GT_SHORTS (TB * GSTRIDE)       // 17728 shorts = 35456 B per buffer

__device__ __forceinline__ unsigned short f2bf(float f) {
    unsigned int u = __float_as_uint(f);
    u += 0x7fff + ((u >> 16) & 1);   // RNE
    return (unsigned short)(u >> 16);
}

// packed f32x2 -> bf16x2 (v_cvt_pk_bf16_f32, RNE)
__device__ __forceinline__ unsigned int pk_bf16(float lo, float hi) {
    float2 f; f.x = lo; f.y = hi;
    __hip_bfloat162 h = __float22bfloat162_rn(f);
    union { __hip_bfloat162 b; unsigned int u; } c;
    c.b = h;
    return c.u;
}

// (256,2): reg cap 256. aW2(96)+aW1(20)+w3v(12)+cf(18)+transients fits with margin -> no spill.
// (256,3) is infeasible: R4/R8 both spilled aW2 (WRITE_SIZE 90-120 MB). Guard: WRITE_SIZE == 10.24 MB.
__global__ __launch_bounds__(256, 2) void lorenz96_fused(
    const float* __restrict__ u,
    const float* __restrict__ coeff,
    const float* __restrict__ W1,
    const float* __restrict__ b1,
    const float* __restrict__ W2,
    const float* __restrict__ b2,
    const float* __restrict__ W3,
    const float* __restrict__ b3,
    float* __restrict__ out)
{
    // LDS: gtile 2x35456 (buf0 aliases W2 staging) + u_sbuf 3200 + out1_sb 2560 = 76672 B
    // -> 2 blocks/CU. Ping-pong: P3(g) and P2(g+1) share one barrier window.
    __shared__ __align__(16) unsigned short gtile[2][GT_SHORTS];
    __shared__ __align__(16) float u_sbuf[2][TB * USTRIDE];   // u_s[b][k] = u[b][(k+36)%40]
    __shared__ float out1_sb[2][TB * 40];

    unsigned short* B_lds = &gtile[0][0];   // alias: consumed into regs before gtile[0] is written

    const int t    = threadIdx.x;
    const int lane = t & 63;
    const int wave = t >> 6;
    const int quad = lane >> 4;
    const int l15  = lane & 15;

    const int b0_block = blockIdx.x * (TB * NBG);

    // ---------- init 0a: W2 staging, pre-swizzled; k=240 carries b2 (bias row, B supplies 1.0) ----------
    // W2eff[o][k = tap*48 + c] = W2[o][c][tap]; lane holds [o = nt*16+l15][k = ks*32+quad*8+j]
    for (int g = t; g < NT * 8 * 64; g += 256) {
        int lg = g & 63;
        int ks = (g >> 6) & 7;
        int nt = g >> 9;
        int o  = nt * 16 + (lg & 15);
        int kb = ks * 32 + (lg >> 4) * 8;
        s16x8 pack = {0, 0, 0, 0, 0, 0, 0, 0};
        #pragma unroll
        for (int j = 0; j < 8; ++j) {
            int k = kb + j;
            if (o < 37) {
                if (k < 240) {
                    int c = k % 48, tap = k / 48;
                    pack[j] = (short)f2bf(W2[o * 240 + c * 5 + tap]);
                } else if (k == 240) {
                    pack[j] = (short)f2bf(b2[o]);
                }
            }
        }
        *(s16x8*)&B_lds[g * 8] = pack;
    }

    // ---------- init 0b: conv1 A-fragments (W1 + fused b1 at k=5) ----------
    // tiles: T0=ch0-15, T1=ch16-31, T2=ch32-47, T3 rows8-15=ch48-55, T4=ch56-71.
    // GLU in-lane: T1 rows8-15 x T3 rows8-15; T2 x T4 (same quad,reg).
    s16x8 aW1[5];
    {
        int chs[5];
        chs[0] = l15; chs[1] = 16 + l15; chs[2] = 32 + l15;
        chs[3] = (l15 >= 8) ? 40 + l15 : -1;
        chs[4] = 56 + l15;
        #pragma unroll
        for (int mt = 0; mt < 5; ++mt) {
            s16x8 a = {0, 0, 0, 0, 0, 0, 0, 0};
            int ch = chs[mt];
            if (quad == 0 && ch >= 0) {
                #pragma unroll
                for (int j = 0; j < 5; ++j) a[j] = (short)f2bf(W1[ch * 5 + j]);
                a[5] = (short)f2bf(b1[ch]);   // bias slot; B supplies 1.0 at k=5
            }
            aW1[mt] = a;
        }
    }

    // ---------- init 0c: epilogue constants (b2 folded into GEMM; only W3 left) ----------
    float w3v[NT][4];
    #pragma unroll
    for (int nt = 0; nt < NT; ++nt)
        #pragma unroll
        for (int r = 0; r < 4; ++r) {
            int o = nt * 16 + quad * 4 + r;
            w3v[nt][r] = (o < 37) ? W3[o] : 0.f;
        }
    const float b3v = b3[0];
    float cf[18];
    #pragma unroll
    for (int i = 0; i < 18; ++i) cf[i] = coeff[i];

    // ---------- helpers ----------
    auto prestage_u = [&](int grp) {   // stage u halo for group grp into u_sbuf[grp&1]
        for (int idx = t; idx < TB * USTRIDE; idx += 256) {
            int b = idx / USTRIDE, k = idx - b * USTRIDE;
            int gi = k + 36; gi -= (gi >= 40) ? 40 : 0; gi -= (gi >= 40) ? 40 : 0;
            u_sbuf[grp & 1][idx] = u[(size_t)(b0_block + grp * TB + b) * 40 + gi];
        }
    };

    auto poly = [&](int grp) {         // polynomial term for this wave's output rows
        const float* u_s = u_sbuf[grp & 1];
        float* o1 = out1_sb[grp & 1];
        #pragma unroll
        for (int pass = 0; pass < 2; ++pass) {
            int i = pass ? 4 : quad;
            bool act = pass ? (quad == 0) : true;
            if (act) {
                int m = (wave + 4 * i) * 16 + l15;
                int p = m >> 3, b = m & 7;
                const float* us = &u_s[b * USTRIDE + p];
                float um2 = us[2], um1 = us[3], u0 = us[4], up1 = us[5], up2 = us[6];
                float r = cf[0] + cf[1]*um2 + cf[2]*um1 + cf[3]*u0 + cf[4]*up1 + cf[5]*up2
                        + cf[6]*um2*um2 + cf[7]*um1*um1 + cf[8]*u0*u0 + cf[9]*up1*up1 + cf[10]*up2*up2
                        + cf[11]*um2*um1 + cf[12]*um1*u0 + cf[13]*u0*up1 + cf[14]*up1*up2
                        + cf[15]*um2*u0 + cf[16]*um1*up1 + cf[17]*u0*up2;
                o1[m] = r;
            }
        }
    };

    auto phase2 = [&](int grp) {       // conv1 via MFMA + GLU -> gtile[grp&1]
        const float* u_s = u_sbuf[grp & 1];
        unsigned short* gt = &gtile[grp & 1][0];
        #pragma unroll
        for (int i = 0; i < 6; ++i) {
            const int ct = wave + 4 * i;               // col-tiles 0..22 live (cols 0..367)
            if (ct > 22) continue;                      // only wave3,i=5: cols 368+ are pad (h>=46)
            const int col = ct * 16 + l15;
            const int b = col & 7, h = col >> 3;        // h <= 45 < HALO always
            s16x8 bU = {0, 0, 0, 0, 0, 0, 0, 0};
            if (quad == 0) {
                const float* us = &u_s[b * USTRIDE + h];   // taps u[(h-4+j)%40], j=0..4
                union { s16x8 v; unsigned int w[4]; } bu;
                bu.w[0] = pk_bf16(us[0], us[1]);
                bu.w[1] = pk_bf16(us[2], us[3]);
                bu.w[2] = pk_bf16(us[4], 1.0f);            // 1.0 -> bias slot k=5
                bu.w[3] = 0;
                bU = bu.v;
            }
            f32x4 a0 = {0.f,0.f,0.f,0.f}, a1 = a0, a2 = a0, a3 = a0, a4 = a0;
            a0 = __builtin_amdgcn_mfma_f32_16x16x32_bf16(aW1[0], bU, a0, 0, 0, 0);
            a1 = __builtin_amdgcn_mfma_f32_16x16x32_bf16(aW1[1], bU, a1, 0, 0, 0);
            a2 = __builtin_amdgcn_mfma_f32_16x16x32_bf16(aW1[2], bU, a2, 0, 0, 0);
            a3 = __builtin_amdgcn_mfma_f32_16x16x32_bf16(aW1[3], bU, a3, 0, 0, 0);
            a4 = __builtin_amdgcn_mfma_f32_16x16x32_bf16(aW1[4], bU, a4, 0, 0, 0);
            float v0[4], v1[4], v2[4];
            #pragma unroll
            for (int r = 0; r < 4; ++r) {
                v0[r] = fmaxf(a0[r], 0.f);
                v1[r] = fmaxf(a1[r], 0.f);
                if (quad >= 2) v1[r] *= fmaxf(a3[r], 0.f);          // ch24-31 gate
                v2[r] = fmaxf(a2[r], 0.f) * fmaxf(a4[r], 0.f);      // ch32-47 gate
            }
            union { s16x4 v; unsigned int w[2]; } w0, w1, w2;
            w0.w[0] = pk_bf16(v0[0], v0[1]); w0.w[1] = pk_bf16(v0[2], v0[3]);
            w1.w[0] = pk_bf16(v1[0], v1[1]); w1.w[1] = pk_bf16(v1[2], v1[3]);
            w2.w[0] = pk_bf16(v2[0], v2[1]); w2.w[1] = pk_bf16(v2[2], v2[3]);
            unsigned short* gp = &gt[b * GSTRIDE + h * 48 + quad * 4];
            *(s16x4*)(gp)      = w0.v;
            *(s16x4*)(gp + 16) = w1.v;
            *(s16x4*)(gp + 32) = w2.v;
        }
    };

    // ---------- prologue ----------
    prestage_u(0);
    __syncthreads();   // B1: B_lds + u_sbuf[0] ready

    // stage-2 A-fragments (W2 + b2 row), all 3 N-tiles per wave -> 3 independent MFMA chains
    s16x8 aW2[NT][8];
    #pragma unroll
    for (int nt = 0; nt < NT; ++nt)
        #pragma unroll
        for (int ks = 0; ks < 8; ++ks)
            aW2[nt][ks] = *(const s16x8*)&B_lds[((nt * 8 + ks) * 64 + lane) * 8];

    poly(0);
    prestage_u(1);
    __syncthreads();   // B2: aW2 fragment reads done -> safe to overwrite gtile[0]

    phase2(0);
    __syncthreads();   // B3: gtile[0] + out1_sb[0] ready

    // ---------- main loop: one barrier per window; P3(g) || P2(g+1) on opposite buffers ----------
    for (int g = 0; g < NBG; ++g) {
        const int b0 = b0_block + g * TB;
        const unsigned short* gt = &gtile[g & 1][0];
        const float* o1 = out1_sb[g & 1];

        // phase 3: each wave: 5 M-tiles x all 3 N-tiles (3 indep chains, shared bg)
        #pragma unroll
        for (int i = 0; i < 5; ++i) {
            const int mt = wave + 4 * i;               // 20 M-tiles (320 G-rows)
            const int m  = mt * 16 + l15;
            const int p  = m >> 3, b = m & 7;
            const unsigned short* gbase = &gt[b * GSTRIDE + p * 48 + quad * 8];
            s16x8 bg[8];
            #pragma unroll
            for (int ks = 0; ks < 8; ++ks) bg[ks] = *(const s16x8*)(gbase + ks * 32);
            {   // bias row: B[k=240][*] must be 1.0 (k=240 <-> ks=7, quad=2, j=0)
                s16x8 b7 = bg[7];
                if (quad == 2) b7[0] = (short)0x3F80;
                bg[7] = b7;
            }
            f32x4 c0 = {0.f,0.f,0.f,0.f}, c1 = c0, c2 = c0;
            #pragma unroll
            for (int ks = 0; ks < 8; ++ks) {
                c0 = __builtin_amdgcn_mfma_f32_16x16x32_bf16(aW2[0][ks], bg[ks], c0, 0, 0, 0);
                c1 = __builtin_amdgcn_mfma_f32_16x16x32_bf16(aW2[1][ks], bg[ks], c1, 0, 0, 0);
                c2 = __builtin_amdgcn_mfma_f32_16x16x32_bf16(aW2[2][ks], bg[ks], c2, 0, 0, 0);
            }
            // epilogue: c already includes b2; sum relu(h2)*W3 over channels, 2 shuffles
            float s = 0.f;
            #pragma unroll
            for (int r = 0; r < 4; ++r) {
                s += fmaxf(c0[r], 0.f) * w3v[0][r];
                s += fmaxf(c1[r], 0.f) * w3v[1][r];
                s += fmaxf(c2[r], 0.f) * w3v[2][r];
            }
            s += __shfl_xor(s, 16, 64);                // sum the 4 quads
            s += __shfl_xor(s, 32, 64);
            if (lane < 16) {
                int mo = mt * 16 + lane;
                out[(size_t)(b0 + (mo & 7)) * 40 + (mo >> 3)] = s + b3v + o1[mo];
            }
        }

        if (g + 1 < NBG) {
            poly(g + 1);                 // writes out1_sb[(g+1)&1]
            phase2(g + 1);               // writes gtile[(g+1)&1] (opposite buffer of P3 above)
            if (g + 2 < NBG) prestage_u(g + 2);
            __syncthreads();             // window barrier: gtile[(g+1)&1] + out1_sb[(g+1)&1] ready
        }
    }
}

extern "C" void kernel_launch(void* const* d_in, const int* in_sizes, int n_in,
                              void* d_out, int out_size, void* d_ws, size_t ws_size,
                              hipStream_t stream) {
    // inputs: 0=t(unused), 1=u, 2=coeff, 3=W1, 4=b1, 5=W2, 6=b2, 7=W3, 8=b3
    const float* u     = (const float*)d_in[1];
    const float* coeff = (const float*)d_in[2];
    const float* W1    = (const float*)d_in[3];
    const float* b1    = (const float*)d_in[4];
    const float* W2    = (const float*)d_in[5];
    const float* b2    = (const float*)d_in[6];
    const float* W3    = (const float*)d_in[7];
    const float* b3    = (const float*)d_in[8];
    float* out = (float*)d_out;

    const int n_batch = in_sizes[1] / 40;            // 65536
    const int grid = n_batch / (TB * NBG);           // 512 blocks = one full 2-blocks/CU round
    lorenz96_fused<<<grid, 256, 0, stream>>>(u, coeff, W1, b1, W2, b2, W3, b3, out);
}

// Round 11
// 186.830 us; speedup vs baseline: 1.2142x; 1.0002x over previous
//
#include <hip/hip_runtime.h>
#include <hip/hip_bf16.h>

typedef short s16x8 __attribute__((ext_vector_type(8)));
typedef short s16x4 __attribute__((ext_vector_type(4)));
typedef float f32x4 __attribute__((ext_vector_type(4)));

#define TB 8            // batch elements per group
#define NBG 16          // groups per block; grid 512 = exactly 2 blocks/CU
#define HALO 46         // live gtile positions per batch (pos -2 .. 43); row 46 = scratch
#define GSTRIDE 2264    // shorts per batch: 47 rows*48=2256 pad to 8*283 (odd): bank-decorrelated
#define USTRIDE 50      // floats per batch in u_s halo
#define NT 3            // stage-2 N tiles (48 cols, >=37 zero-padded; k=240 = b2 row)
#define GT_SHORTS (TB * GSTRIDE)       // 18112 shorts = 36224 B per buffer

__device__ __forceinline__ unsigned short f2bf(float f) {
    unsigned int u = __float_as_uint(f);
    u += 0x7fff + ((u >> 16) & 1);   // RNE
    return (unsigned short)(u >> 16);
}

// packed f32x2 -> bf16x2 (v_cvt_pk_bf16_f32, RNE)
__device__ __forceinline__ unsigned int pk_bf16(float lo, float hi) {
    float2 f; f.x = lo; f.y = hi;
    __hip_bfloat162 h = __float22bfloat162_rn(f);
    union { __hip_bfloat162 b; unsigned int u; } c;
    c.b = h;
    return c.u;
}

// (256,2): combined VGPR+AGPR cap 256/wave. (256,3) hard-spills aW2 (R4/R8: WRITE_SIZE 90-120MB).
// Guards: WRITE_SIZE == 10.24 MB, VGPR_Count <= ~200.
__global__ __launch_bounds__(256, 2) void lorenz96_fused(
    const float* __restrict__ u,
    const float* __restrict__ coeff,
    const float* __restrict__ W1,
    const float* __restrict__ b1,
    const float* __restrict__ W2,
    const float* __restrict__ b2,
    const float* __restrict__ W3,
    const float* __restrict__ b3,
    float* __restrict__ out)
{
    // LDS: gtile 2x36224 (buf0 aliases W2 staging) + u_sbuf 3200 + out1_sb 2560 = 78208 B -> 2 blocks/CU
    __shared__ __align__(16) unsigned short gtile[2][GT_SHORTS];
    __shared__ __align__(16) float u_sbuf[2][TB * USTRIDE];   // u_s[b][k] = u[b][(k+36)%40]
    __shared__ float out1_sb[2][TB * 40];

    unsigned short* B_lds = &gtile[0][0];   // alias: consumed into regs before gtile[0] is written

    const int t    = threadIdx.x;
    const int lane = t & 63;
    const int wave = t >> 6;
    const int quad = lane >> 4;
    const int l15  = lane & 15;

    const int b0_block = blockIdx.x * (TB * NBG);

    // ---------- init 0a: W2 staging, pre-swizzled; k=240 carries b2 (bias row, B supplies 1.0) ----------
    // W2eff[o][k = tap*48 + c] = W2[o][c][tap]; lane holds [o = nt*16+l15][k = ks*32+quad*8+j]
    for (int g = t; g < NT * 8 * 64; g += 256) {
        int lg = g & 63;
        int ks = (g >> 6) & 7;
        int nt = g >> 9;
        int o  = nt * 16 + (lg & 15);
        int kb = ks * 32 + (lg >> 4) * 8;
        s16x8 pack = {0, 0, 0, 0, 0, 0, 0, 0};
        #pragma unroll
        for (int j = 0; j < 8; ++j) {
            int k = kb + j;
            if (o < 37) {
                if (k < 240) {
                    int c = k % 48, tap = k / 48;
                    pack[j] = (short)f2bf(W2[o * 240 + c * 5 + tap]);
                } else if (k == 240) {
                    pack[j] = (short)f2bf(b2[o]);
                }
            }
        }
        *(s16x8*)&B_lds[g * 8] = pack;
    }

    // ---------- init 0b: conv1 A-fragments (W1 + fused b1 at k=5) ----------
    // tiles: T0=ch0-15, T1=ch16-31, T2=ch32-47, T3 rows8-15=ch48-55, T4=ch56-71.
    // GLU in-lane: T1 rows8-15 x T3 rows8-15; T2 x T4 (same quad,reg).
    s16x8 aW1[5];
    {
        int chs[5];
        chs[0] = l15; chs[1] = 16 + l15; chs[2] = 32 + l15;
        chs[3] = (l15 >= 8) ? 40 + l15 : -1;
        chs[4] = 56 + l15;
        #pragma unroll
        for (int mt = 0; mt < 5; ++mt) {
            s16x8 a = {0, 0, 0, 0, 0, 0, 0, 0};
            int ch = chs[mt];
            if (quad == 0 && ch >= 0) {
                #pragma unroll
                for (int j = 0; j < 5; ++j) a[j] = (short)f2bf(W1[ch * 5 + j]);
                a[5] = (short)f2bf(b1[ch]);   // bias slot; B supplies 1.0 at k=5
            }
            aW1[mt] = a;
        }
    }

    // ---------- init 0c: epilogue constants (b2 folded into GEMM; only W3 left) ----------
    float w3v[NT][4];
    #pragma unroll
    for (int nt = 0; nt < NT; ++nt)
        #pragma unroll
        for (int r = 0; r < 4; ++r) {
            int o = nt * 16 + quad * 4 + r;
            w3v[nt][r] = (o < 37) ? W3[o] : 0.f;
        }
    const float b3v = b3[0];
    float cf[18];
    #pragma unroll
    for (int i = 0; i < 18; ++i) cf[i] = coeff[i];

    // stage-2 A-fragments (declared before lambdas so they capture it)
    s16x8 aW2[NT][8];

    // ---------- helpers ----------
    auto prestage_u = [&](int grp) {   // stage u halo for group grp into u_sbuf[grp&1]
        for (int idx = t; idx < TB * USTRIDE; idx += 256) {
            int b = idx / USTRIDE, k = idx - b * USTRIDE;
            int gi = k + 36; gi -= (gi >= 40) ? 40 : 0; gi -= (gi >= 40) ? 40 : 0;
            u_sbuf[grp & 1][idx] = u[(size_t)(b0_block + grp * TB + b) * 40 + gi];
        }
    };

    auto poly = [&](int grp) {         // polynomial term for this wave's output rows
        const float* u_s = u_sbuf[grp & 1];
        float* o1 = out1_sb[grp & 1];
        #pragma unroll
        for (int pass = 0; pass < 2; ++pass) {
            int i = pass ? 4 : quad;
            bool act = pass ? (quad == 0) : true;
            if (act) {
                int m = (wave + 4 * i) * 16 + l15;
                int p = m >> 3, b = m & 7;
                const float* us = &u_s[b * USTRIDE + p];
                float um2 = us[2], um1 = us[3], u0 = us[4], up1 = us[5], up2 = us[6];
                float r = cf[0] + cf[1]*um2 + cf[2]*um1 + cf[3]*u0 + cf[4]*up1 + cf[5]*up2
                        + cf[6]*um2*um2 + cf[7]*um1*um1 + cf[8]*u0*u0 + cf[9]*up1*up1 + cf[10]*up2*up2
                        + cf[11]*um2*um1 + cf[12]*um1*u0 + cf[13]*u0*up1 + cf[14]*up1*up2
                        + cf[15]*um2*u0 + cf[16]*um1*up1 + cf[17]*u0*up2;
                o1[m] = r;
            }
        }
    };

    // P2 tile i (branchless): conv1 via MFMA + GLU -> gt.
    // Pad tile ct=23 spans h=46 AND 47 (two rows!); BOTH clamp to scratch row 46 via hs=min(h,46)
    // (duplicate same-wave scratch writes: one lane wins, row 46 never read). R10 bug: h=47
    // overflowed into batch b+1 row 0.
    auto p2_tile = [&](int i, const float* u_s, unsigned short* gt) {
        const int ct  = wave + 4 * i;              // 0..23
        const int col = ct * 16 + l15;
        const int b = col & 7, h = col >> 3;       // h <= 47
        const int hc = (h < HALO) ? h : 0;         // clamp for in-bounds u_s read
        const int hs = (h < HALO) ? h : HALO;      // clamp store to scratch row 46
        const float* us = &u_s[b * USTRIDE + hc];  // taps u[(h-4+j)%40], j=0..4
        float t0 = us[0], t1 = us[1], t2 = us[2], t3 = us[3], t4 = us[4];
        const bool q0 = (quad == 0);
        union { s16x8 v; unsigned int w[4]; } bu;
        bu.w[0] = q0 ? pk_bf16(t0, t1) : 0u;
        bu.w[1] = q0 ? pk_bf16(t2, t3) : 0u;
        bu.w[2] = q0 ? pk_bf16(t4, 1.0f) : 0u;     // 1.0 -> bias slot k=5
        bu.w[3] = 0u;
        f32x4 a0 = {0.f,0.f,0.f,0.f}, a1 = a0, a2 = a0, a3 = a0, a4 = a0;
        a0 = __builtin_amdgcn_mfma_f32_16x16x32_bf16(aW1[0], bu.v, a0, 0, 0, 0);
        a1 = __builtin_amdgcn_mfma_f32_16x16x32_bf16(aW1[1], bu.v, a1, 0, 0, 0);
        a2 = __builtin_amdgcn_mfma_f32_16x16x32_bf16(aW1[2], bu.v, a2, 0, 0, 0);
        a3 = __builtin_amdgcn_mfma_f32_16x16x32_bf16(aW1[3], bu.v, a3, 0, 0, 0);
        a4 = __builtin_amdgcn_mfma_f32_16x16x32_bf16(aW1[4], bu.v, a4, 0, 0, 0);
        float v0[4], v1[4], v2[4];
        #pragma unroll
        for (int r = 0; r < 4; ++r) {
            v0[r] = fmaxf(a0[r], 0.f);
            v1[r] = fmaxf(a1[r], 0.f);
            if (quad >= 2) v1[r] *= fmaxf(a3[r], 0.f);          // ch24-31 gate
            v2[r] = fmaxf(a2[r], 0.f) * fmaxf(a4[r], 0.f);      // ch32-47 gate
        }
        union { s16x4 v; unsigned int w[2]; } w0, w1, w2;
        w0.w[0] = pk_bf16(v0[0], v0[1]); w0.w[1] = pk_bf16(v0[2], v0[3]);
        w1.w[0] = pk_bf16(v1[0], v1[1]); w1.w[1] = pk_bf16(v1[2], v1[3]);
        w2.w[0] = pk_bf16(v2[0], v2[1]); w2.w[1] = pk_bf16(v2[2], v2[3]);
        unsigned short* gp = &gt[b * GSTRIDE + hs * 48 + quad * 4];
        *(s16x4*)(gp)      = w0.v;
        *(s16x4*)(gp + 16) = w1.v;
        *(s16x4*)(gp + 32) = w2.v;
    };

    // P3 tile i: stage-2 GEMM on M-tile (wave+4i) + fused relu/W3 epilogue -> out
    auto p3_tile = [&](int i, const unsigned short* gt, const float* o1, int b0) {
        const int mt = wave + 4 * i;               // 20 M-tiles (320 G-rows)
        const int m  = mt * 16 + l15;
        const int p  = m >> 3, b = m & 7;
        const unsigned short* gbase = &gt[b * GSTRIDE + p * 48 + quad * 8];
        s16x8 bg[8];
        #pragma unroll
        for (int ks = 0; ks < 8; ++ks) bg[ks] = *(const s16x8*)(gbase + ks * 32);
        {   // bias row: B[k=240][*] must read 1.0 (k=240 <-> ks=7, quad=2, j=0)
            s16x8 b7 = bg[7];
            if (quad == 2) b7[0] = (short)0x3F80;
            bg[7] = b7;
        }
        f32x4 c0 = {0.f,0.f,0.f,0.f}, c1 = c0, c2 = c0;
        #pragma unroll
        for (int ks = 0; ks < 8; ++ks) {
            c0 = __builtin_amdgcn_mfma_f32_16x16x32_bf16(aW2[0][ks], bg[ks], c0, 0, 0, 0);
            c1 = __builtin_amdgcn_mfma_f32_16x16x32_bf16(aW2[1][ks], bg[ks], c1, 0, 0, 0);
            c2 = __builtin_amdgcn_mfma_f32_16x16x32_bf16(aW2[2][ks], bg[ks], c2, 0, 0, 0);
        }
        float s = 0.f;
        #pragma unroll
        for (int r = 0; r < 4; ++r) {
            s += fmaxf(c0[r], 0.f) * w3v[0][r];
            s += fmaxf(c1[r], 0.f) * w3v[1][r];
            s += fmaxf(c2[r], 0.f) * w3v[2][r];
        }
        s += __shfl_xor(s, 16, 64);                // sum the 4 quads
        s += __shfl_xor(s, 32, 64);
        if (lane < 16) {
            int mo = mt * 16 + lane;
            out[(size_t)(b0 + (mo & 7)) * 40 + (mo >> 3)] = s + b3v + o1[mo];
        }
    };

    // ---------- prologue ----------
    prestage_u(0);
    __syncthreads();   // B1: B_lds + u_sbuf[0] ready

    #pragma unroll
    for (int nt = 0; nt < NT; ++nt)
        #pragma unroll
        for (int ks = 0; ks < 8; ++ks)
            aW2[nt][ks] = *(const s16x8*)&B_lds[((nt * 8 + ks) * 64 + lane) * 8];

    poly(0);
    prestage_u(1);
    __syncthreads();   // B2: aW2 fragment reads done -> safe to overwrite gtile[0]

    #pragma unroll
    for (int i = 0; i < 6; ++i) p2_tile(i, u_sbuf[0], &gtile[0][0]);
    __syncthreads();   // B3: gtile[0] + out1_sb[0] ready

    // ---------- main loop: fused windows (P3(g) interleaved with P2(g+1)), one barrier each ----------
    for (int g = 0; g < NBG - 1; ++g) {
        const int b0 = b0_block + g * TB;
        const unsigned short* gt   = &gtile[g & 1][0];
        unsigned short*       gtn  = &gtile[(g + 1) & 1][0];
        const float*          o1   = out1_sb[g & 1];
        const float*          u_n  = u_sbuf[(g + 1) & 1];

        if (g + 2 < NBG) prestage_u(g + 2);   // long-latency global loads issued first

        #pragma unroll
        for (int i = 0; i < 6; ++i) {
            if (i < 5) p3_tile(i, gt, o1, b0);   // compile-time guard (unrolled)
            p2_tile(i, u_n, gtn);
        }

        poly(g + 1);
        __syncthreads();   // window barrier: gtile[(g+1)&1] + out1_sb[(g+1)&1] ready
    }

    // ---------- tail window: P3 only ----------
    {
        const int g = NBG - 1;
        const int b0 = b0_block + g * TB;
        #pragma unroll
        for (int i = 0; i < 5; ++i) p3_tile(i, &gtile[g & 1][0], out1_sb[g & 1], b0);
    }
}

extern "C" void kernel_launch(void* const* d_in, const int* in_sizes, int n_in,
                              void* d_out, int out_size, void* d_ws, size_t ws_size,
                              hipStream_t stream) {
    // inputs: 0=t(unused), 1=u, 2=coeff, 3=W1, 4=b1, 5=W2, 6=b2, 7=W3, 8=b3
    const float* u     = (const float*)d_in[1];
    const float* coeff = (const float*)d_in[2];
    const float* W1    = (const float*)d_in[3];
    const float* b1    = (const float*)d_in[4];
    const float* W2    = (const float*)d_in[5];
    const float* b2    = (const float*)d_in[6];
    const float* W3    = (const float*)d_in[7];
    const float* b3    = (const float*)d_in[8];
    float* out = (float*)d_out;

    const int n_batch = in_sizes[1] / 40;            // 65536
    const int grid = n_batch / (TB * NBG);           // 512 blocks = one full 2-blocks/CU round
    lorenz96_fused<<<grid, 256, 0, stream>>>(u, coeff, W1, b1, W2, b2, W3, b3, out);
}

// Round 12
// 182.895 us; speedup vs baseline: 1.2403x; 1.0215x over previous
//
#include <hip/hip_runtime.h>
#include <hip/hip_bf16.h>

typedef short s16x8 __attribute__((ext_vector_type(8)));
typedef short s16x4 __attribute__((ext_vector_type(4)));
typedef float f32x4 __attribute__((ext_vector_type(4)));

#define TB 8            // batch elements per group
#define NBG 16          // groups per block; grid 512 = exactly 2 blocks/CU
#define HALO 46         // gtile positions per batch (pos -2 .. 43)
#define GSTRIDE 2216    // shorts per batch in gtile (8*odd: bank-decorrelated)
#define USTRIDE 50      // floats per batch in u_s halo
#define NT 3            // stage-2 N tiles (48 cols, >=37 zero-padded; k=240 = b2 row)
#define GT_SHORTS (TB * GSTRIDE)       // 17728 shorts = 35456 B per buffer

__device__ __forceinline__ unsigned short f2bf(float f) {
    unsigned int u = __float_as_uint(f);
    u += 0x7fff + ((u >> 16) & 1);   // RNE
    return (unsigned short)(u >> 16);
}

// packed f32x2 -> bf16x2 (v_cvt_pk_bf16_f32, RNE)
__device__ __forceinline__ unsigned int pk_bf16(float lo, float hi) {
    float2 f; f.x = lo; f.y = hi;
    __hip_bfloat162 h = __float22bfloat162_rn(f);
    union { __hip_bfloat162 b; unsigned int u; } c;
    c.b = h;
    return c.u;
}

// (256,2): combined VGPR+AGPR cap 256/wave. (256,3) hard-spills aW2 (R4/R8: WRITE_SIZE 90-120MB).
// Guards: WRITE_SIZE == 10.24 MB, VGPR_Count <= ~200.
__global__ __launch_bounds__(256, 2) void lorenz96_fused(
    const float* __restrict__ u,
    const float* __restrict__ coeff,
    const float* __restrict__ W1,
    const float* __restrict__ b1,
    const float* __restrict__ W2,
    const float* __restrict__ b2,
    const float* __restrict__ W3,
    const float* __restrict__ b3,
    float* __restrict__ out)
{
    // LDS: gtile 2x35456 (buf0 aliases W2 staging) + u_sbuf 3200 = 74112 B -> 2 blocks/CU
    // (out1 LDS array eliminated: poly term lives in registers, carried across one barrier)
    __shared__ __align__(16) unsigned short gtile[2][GT_SHORTS];
    __shared__ __align__(16) float u_sbuf[2][TB * USTRIDE];   // u_s[b][k] = u[b][(k+36)%40]

    unsigned short* B_lds = &gtile[0][0];   // alias: consumed into regs before gtile[0] is written

    const int t    = threadIdx.x;
    const int lane = t & 63;
    const int wave = t >> 6;
    const int quad = lane >> 4;
    const int l15  = lane & 15;

    const int b0_block = blockIdx.x * (TB * NBG);

    // ---------- init 0a: W2 staging, pre-swizzled; k=240 carries b2 (bias row, B supplies 1.0) ----------
    // W2eff[o][k = tap*48 + c] = W2[o][c][tap]; lane holds [o = nt*16+l15][k = ks*32+quad*8+j]
    for (int g = t; g < NT * 8 * 64; g += 256) {
        int lg = g & 63;
        int ks = (g >> 6) & 7;
        int nt = g >> 9;
        int o  = nt * 16 + (lg & 15);
        int kb = ks * 32 + (lg >> 4) * 8;
        s16x8 pack = {0, 0, 0, 0, 0, 0, 0, 0};
        #pragma unroll
        for (int j = 0; j < 8; ++j) {
            int k = kb + j;
            if (o < 37) {
                if (k < 240) {
                    int c = k % 48, tap = k / 48;
                    pack[j] = (short)f2bf(W2[o * 240 + c * 5 + tap]);
                } else if (k == 240) {
                    pack[j] = (short)f2bf(b2[o]);
                }
            }
        }
        *(s16x8*)&B_lds[g * 8] = pack;
    }

    // ---------- init 0b: conv1 A-fragments (W1 + fused b1 at k=5) ----------
    // tiles: T0=ch0-15, T1=ch16-31, T2=ch32-47, T3 rows8-15=ch48-55, T4=ch56-71.
    // GLU in-lane: T1 rows8-15 x T3 rows8-15; T2 x T4 (same quad,reg).
    s16x8 aW1[5];
    {
        int chs[5];
        chs[0] = l15; chs[1] = 16 + l15; chs[2] = 32 + l15;
        chs[3] = (l15 >= 8) ? 40 + l15 : -1;
        chs[4] = 56 + l15;
        #pragma unroll
        for (int mt = 0; mt < 5; ++mt) {
            s16x8 a = {0, 0, 0, 0, 0, 0, 0, 0};
            int ch = chs[mt];
            if (quad == 0 && ch >= 0) {
                #pragma unroll
                for (int j = 0; j < 5; ++j) a[j] = (short)f2bf(W1[ch * 5 + j]);
                a[5] = (short)f2bf(b1[ch]);   // bias slot; B supplies 1.0 at k=5
            }
            aW1[mt] = a;
        }
    }

    // ---------- init 0c: epilogue constants (b2 folded into GEMM; only W3 left) ----------
    float w3v[NT][4];
    #pragma unroll
    for (int nt = 0; nt < NT; ++nt)
        #pragma unroll
        for (int r = 0; r < 4; ++r) {
            int o = nt * 16 + quad * 4 + r;
            w3v[nt][r] = (o < 37) ? W3[o] : 0.f;
        }
    const float b3v = b3[0];
    float cf[18];
    #pragma unroll
    for (int i = 0; i < 18; ++i) cf[i] = coeff[i];

    // stage-2 A-fragments (declared before lambdas so they capture it)
    s16x8 aW2[NT][8];
    // poly term registers: pv_q = row of tile i=quad; pv_4 = row of tile i=4 (valid on quad 0)
    float pv_q = 0.f, pv_4 = 0.f;

    // ---------- helpers ----------
    auto prestage_u = [&](int grp) {   // stage u halo for group grp into u_sbuf[grp&1]
        for (int idx = t; idx < TB * USTRIDE; idx += 256) {
            int b = idx / USTRIDE, k = idx - b * USTRIDE;
            int gi = k + 36; gi -= (gi >= 40) ? 40 : 0; gi -= (gi >= 40) ? 40 : 0;
            u_sbuf[grp & 1][idx] = u[(size_t)(b0_block + grp * TB + b) * 40 + gi];
        }
    };

    auto poly1 = [&](const float* u_s, int m) -> float {   // poly term for output row m
        int p = m >> 3, b = m & 7;
        const float* us = &u_s[b * USTRIDE + p];
        float um2 = us[2], um1 = us[3], u0 = us[4], up1 = us[5], up2 = us[6];
        return cf[0] + cf[1]*um2 + cf[2]*um1 + cf[3]*u0 + cf[4]*up1 + cf[5]*up2
             + cf[6]*um2*um2 + cf[7]*um1*um1 + cf[8]*u0*u0 + cf[9]*up1*up1 + cf[10]*up2*up2
             + cf[11]*um2*um1 + cf[12]*um1*u0 + cf[13]*u0*up1 + cf[14]*up1*up2
             + cf[15]*um2*u0 + cf[16]*um1*up1 + cf[17]*u0*up2;
    };

    auto poly = [&](int grp) {         // fill pv_q / pv_4 for group grp (in-register, no LDS)
        const float* u_s = u_sbuf[grp & 1];
        pv_q = poly1(u_s, (wave + 4 * quad) * 16 + l15);   // row of this wave's tile i=quad
        pv_4 = poly1(u_s, (wave + 16) * 16 + l15);         // row of tile i=4 (used by quad 0)
    };

    auto phase2 = [&](int grp) {       // conv1 via MFMA + GLU -> gtile[grp&1]
        const float* u_s = u_sbuf[grp & 1];
        unsigned short* gt = &gtile[grp & 1][0];
        #pragma unroll
        for (int i = 0; i < 6; ++i) {
            const int ct = wave + 4 * i;               // col-tiles 0..22 live (cols 0..367)
            if (ct > 22) continue;                      // only wave3,i=5: cols 368+ are pad
            const int col = ct * 16 + l15;
            const int b = col & 7, h = col >> 3;        // h <= 45 < HALO always
            s16x8 bU = {0, 0, 0, 0, 0, 0, 0, 0};
            if (quad == 0) {                            // exec-masked: only 16 lanes touch LDS
                const float* us = &u_s[b * USTRIDE + h];   // taps u[(h-4+j)%40], j=0..4
                union { s16x8 v; unsigned int w[4]; } bu;
                bu.w[0] = pk_bf16(us[0], us[1]);
                bu.w[1] = pk_bf16(us[2], us[3]);
                bu.w[2] = pk_bf16(us[4], 1.0f);            // 1.0 -> bias slot k=5
                bu.w[3] = 0;
                bU = bu.v;
            }
            f32x4 a0 = {0.f,0.f,0.f,0.f}, a1 = a0, a2 = a0, a3 = a0, a4 = a0;
            a0 = __builtin_amdgcn_mfma_f32_16x16x32_bf16(aW1[0], bU, a0, 0, 0, 0);
            a1 = __builtin_amdgcn_mfma_f32_16x16x32_bf16(aW1[1], bU, a1, 0, 0, 0);
            a2 = __builtin_amdgcn_mfma_f32_16x16x32_bf16(aW1[2], bU, a2, 0, 0, 0);
            a3 = __builtin_amdgcn_mfma_f32_16x16x32_bf16(aW1[3], bU, a3, 0, 0, 0);
            a4 = __builtin_amdgcn_mfma_f32_16x16x32_bf16(aW1[4], bU, a4, 0, 0, 0);
            float v0[4], v1[4], v2[4];
            #pragma unroll
            for (int r = 0; r < 4; ++r) {
                v0[r] = fmaxf(a0[r], 0.f);
                v1[r] = fmaxf(a1[r], 0.f);
                if (quad >= 2) v1[r] *= fmaxf(a3[r], 0.f);          // ch24-31 gate
                v2[r] = fmaxf(a2[r], 0.f) * fmaxf(a4[r], 0.f);      // ch32-47 gate
            }
            union { s16x4 v; unsigned int w[2]; } w0, w1, w2;
            w0.w[0] = pk_bf16(v0[0], v0[1]); w0.w[1] = pk_bf16(v0[2], v0[3]);
            w1.w[0] = pk_bf16(v1[0], v1[1]); w1.w[1] = pk_bf16(v1[2], v1[3]);
            w2.w[0] = pk_bf16(v2[0], v2[1]); w2.w[1] = pk_bf16(v2[2], v2[3]);
            unsigned short* gp = &gt[b * GSTRIDE + h * 48 + quad * 4];
            *(s16x4*)(gp)      = w0.v;
            *(s16x4*)(gp + 16) = w1.v;
            *(s16x4*)(gp + 32) = w2.v;
        }
    };

    // P3 tile i: stage-2 GEMM on M-tile (wave+4i) + fused relu/W3 epilogue -> out.
    // Store done by quad i (i<4) with pv_q, or quad 0 (i=4) with pv_4: the poly value for
    // row mt*16+l15 lives exactly in that quad's register (poly's quad-distributed layout).
    auto p3_tile = [&](int i, const unsigned short* gt, int b0) {
        const int mt = wave + 4 * i;               // 20 M-tiles (320 G-rows)
        const int m  = mt * 16 + l15;
        const int p  = m >> 3, b = m & 7;
        const unsigned short* gbase = &gt[b * GSTRIDE + p * 48 + quad * 8];
        s16x8 bg[8];
        #pragma unroll
        for (int ks = 0; ks < 8; ++ks) bg[ks] = *(const s16x8*)(gbase + ks * 32);
        {   // bias row: B[k=240][*] must read 1.0 (k=240 <-> ks=7, quad=2, j=0)
            s16x8 b7 = bg[7];
            if (quad == 2) b7[0] = (short)0x3F80;
            bg[7] = b7;
        }
        f32x4 c0 = {0.f,0.f,0.f,0.f}, c1 = c0, c2 = c0;
        #pragma unroll
        for (int ks = 0; ks < 8; ++ks) {
            c0 = __builtin_amdgcn_mfma_f32_16x16x32_bf16(aW2[0][ks], bg[ks], c0, 0, 0, 0);
            c1 = __builtin_amdgcn_mfma_f32_16x16x32_bf16(aW2[1][ks], bg[ks], c1, 0, 0, 0);
            c2 = __builtin_amdgcn_mfma_f32_16x16x32_bf16(aW2[2][ks], bg[ks], c2, 0, 0, 0);
        }
        float s = 0.f;
        #pragma unroll
        for (int r = 0; r < 4; ++r) {
            s += fmaxf(c0[r], 0.f) * w3v[0][r];
            s += fmaxf(c1[r], 0.f) * w3v[1][r];
            s += fmaxf(c2[r], 0.f) * w3v[2][r];
        }
        s += __shfl_xor(s, 16, 64);                // sum the 4 quads (full sum in every lane)
        s += __shfl_xor(s, 32, 64);
        const float pv = (i < 4) ? pv_q : pv_4;
        const bool  st = (i < 4) ? (quad == i) : (quad == 0);
        if (st) {
            // row m = mt*16 + l15 -> out[b0 + (m&7)][m>>3]
            out[(size_t)(b0 + (l15 & 7)) * 40 + 2 * mt + (l15 >> 3)] = s + b3v + pv;
        }
    };

    // ---------- prologue ----------
    prestage_u(0);
    __syncthreads();   // B1: B_lds + u_sbuf[0] ready

    #pragma unroll
    for (int nt = 0; nt < NT; ++nt)
        #pragma unroll
        for (int ks = 0; ks < 8; ++ks)
            aW2[nt][ks] = *(const s16x8*)&B_lds[((nt * 8 + ks) * 64 + lane) * 8];

    poly(0);           // pv regs for group 0
    prestage_u(1);
    __syncthreads();   // B2: aW2 fragment reads done -> safe to overwrite gtile[0]

    phase2(0);
    __syncthreads();   // B3: gtile[0] ready

    // ---------- main loop: windows; P3(g), then produce group g+1 ----------
    for (int g = 0; g < NBG; ++g) {
        const int b0 = b0_block + g * TB;
        const unsigned short* gt = &gtile[g & 1][0];

        #pragma unroll
        for (int i = 0; i < 5; ++i) p3_tile(i, gt, b0);   // consumes pv (group g)

        if (g + 1 < NBG) {
            poly(g + 1);                 // overwrites pv regs for group g+1
            phase2(g + 1);               // writes gtile[(g+1)&1] (opposite buffer)
            if (g + 2 < NBG) prestage_u(g + 2);
            __syncthreads();             // window barrier: gtile[(g+1)&1] ready
        }
    }
}

extern "C" void kernel_launch(void* const* d_in, const int* in_sizes, int n_in,
                              void* d_out, int out_size, void* d_ws, size_t ws_size,
                              hipStream_t stream) {
    // inputs: 0=t(unused), 1=u, 2=coeff, 3=W1, 4=b1, 5=W2, 6=b2, 7=W3, 8=b3
    const float* u     = (const float*)d_in[1];
    const float* coeff = (const float*)d_in[2];
    const float* W1    = (const float*)d_in[3];
    const float* b1    = (const float*)d_in[4];
    const float* W2    = (const float*)d_in[5];
    const float* b2    = (const float*)d_in[6];
    const float* W3    = (const float*)d_in[7];
    const float* b3    = (const float*)d_in[8];
    float* out = (float*)d_out;

    const int n_batch = in_sizes[1] / 40;            // 65536
    const int grid = n_batch / (TB * NBG);           // 512 blocks = one full 2-blocks/CU round
    lorenz96_fused<<<grid, 256, 0, stream>>>(u, coeff, W1, b1, W2, b2, W3, b3, out);
}